// Round 13
// baseline (50.228 us; speedup 1.0000x reference)
//
#include <hip/hip_runtime.h>
#include <hip/hip_bf16.h>
#include <stdint.h>

// Shapes (fixed by the problem)
constexpr int Bsz  = 4;
constexpr int Nseq = 1024;
constexpr int Cdim = 1024;
constexpr int Mrows = Bsz * Nseq;   // 4096
constexpr int KD = 1024;            // GEMM K (both GEMMs)
constexpr int BK = 64;              // K-step
constexpr int NT = KD / BK;         // 16 K-steps

typedef __attribute__((ext_vector_type(8))) short s16x8;
typedef __attribute__((ext_vector_type(4))) float f32x4;
typedef __attribute__((address_space(3))) unsigned char lds_b;
typedef __attribute__((address_space(1))) const unsigned char gbl_b;

__device__ inline short bf16_rne(float f) {
    union { float f; unsigned u; } c; c.f = f;
    unsigned u = c.u;
    u = u + 0x7FFFu + ((u >> 16) & 1u);
    return (short)(u >> 16);
}

template <int N> __device__ __forceinline__ void waitv() {
    if constexpr (N == 0)      asm volatile("s_waitcnt vmcnt(0)" ::: "memory");
    else if constexpr (N == 4) asm volatile("s_waitcnt vmcnt(4)" ::: "memory");
    else if constexpr (N == 8) asm volatile("s_waitcnt vmcnt(8)" ::: "memory");
    else static_assert(N == 0, "unsupported vmcnt");
}

// ---------------------------------------------------------------------------
// K1: fused prep + mask-average (grid 4608 x 256)  [R9-proven, unchanged]:
//   blocks [0,256):    wvT = bf16(Wv^T)          (64x64 LDS transpose tiles)
//   blocks [256,512):  bias2 = pw@bv+pb ; pwb = bf16(pw)
//   blocks [512,4608): Zb[row,:] = bf16(mean over argmax-mask cols j of x[b,j,:])
//                      XCD-grouped rows: each XCD gathers from ONE 4MB batch
//                      slice of f32 x -> L2-resident gather.
__global__ __launch_bounds__(256) void prep_mask_kernel(
        const float* __restrict__ x, const int* __restrict__ mask,
        const float* __restrict__ Wv, const float* __restrict__ pw,
        const float* __restrict__ bv, const float* __restrict__ pb,
        ushort* __restrict__ wvT, ushort* __restrict__ pwb,
        float* __restrict__ bias2, ushort* __restrict__ Zb) {
    const int bid = blockIdx.x;
    const int tid = threadIdx.x;
    if (bid < 256) {
        // ---- transpose-convert Wv -> wvT
        __shared__ ushort t[64][72];
        const int r0 = (bid >> 4) * 64, c0 = (bid & 15) * 64;
        const int lr = tid >> 4;
        const int lc = (tid & 15) * 4;
        #pragma unroll
        for (int p = 0; p < 4; ++p) {
            const int row = p * 16 + lr;
            const float4 v = *(const float4*)(Wv + (size_t)(r0 + row) * Cdim + c0 + lc);
            t[lc + 0][row] = (ushort)bf16_rne(v.x);
            t[lc + 1][row] = (ushort)bf16_rne(v.y);
            t[lc + 2][row] = (ushort)bf16_rne(v.z);
            t[lc + 3][row] = (ushort)bf16_rne(v.w);
        }
        __syncthreads();
        const int orow = tid >> 2;
        const int oc   = (tid & 3) * 16;
        const s16x8 a = *(const s16x8*)&t[orow][oc];
        const s16x8 b = *(const s16x8*)&t[orow][oc + 8];
        ushort* d = wvT + (size_t)(c0 + orow) * Cdim + r0 + oc;
        *(s16x8*)d = a;
        *(s16x8*)(d + 8) = b;
        return;
    }
    if (bid < 512) {
        // ---- bias2 + pw convert (one wave per row)
        const int j = (bid - 256) * 4 + (tid >> 6);
        const int l = tid & 63;
        float s = 0.f;
        #pragma unroll
        for (int c = 0; c < 4; ++c) {
            const float4 w = *(const float4*)(pw + (size_t)j * Cdim + c * 256 + l * 4);
            const float4 b = *(const float4*)(bv + c * 256 + l * 4);
            s += w.x * b.x + w.y * b.y + w.z * b.z + w.w * b.w;
            ushort4 o;
            o.x = (ushort)bf16_rne(w.x); o.y = (ushort)bf16_rne(w.y);
            o.z = (ushort)bf16_rne(w.z); o.w = (ushort)bf16_rne(w.w);
            *(ushort4*)(pwb + (size_t)j * Cdim + c * 256 + l * 4) = o;
        }
        #pragma unroll
        for (int off = 32; off > 0; off >>= 1) s += __shfl_xor(s, off);
        if (l == 0) bias2[j] = s + pb[j];
        return;
    }
    // ---- mask-average over f32 x (XCD-grouped rows)
    __shared__ int wmax[4];
    __shared__ int wtot[4];
    __shared__ int idx[1024];
    const int m   = bid - 512;
    const int row = (m & 7) * 512 + (m >> 3);   // XCD k -> rows [k*512,(k+1)*512)
    const int lane = tid & 63;
    const int w = tid >> 6;
    const int b = row >> 10;
    const int* mrow = mask + (size_t)row * Nseq;

    const int4 mv = ((const int4*)mrow)[tid];
    int lm = max(max(mv.x, mv.y), max(mv.z, mv.w));
    #pragma unroll
    for (int off = 32; off > 0; off >>= 1) lm = max(lm, __shfl_xor(lm, off));
    if (lane == 0) wmax[w] = lm;
    __syncthreads();
    const int gmax = max(max(wmax[0], wmax[1]), max(wmax[2], wmax[3]));

    const int loc = (mv.x == gmax) + (mv.y == gmax) + (mv.z == gmax) + (mv.w == gmax);
    int s = loc;   // inclusive shfl-scan within the wave
    #pragma unroll
    for (int off = 1; off < 64; off <<= 1) {
        const int o = __shfl_up(s, off, 64);
        if (lane >= off) s += o;
    }
    if (lane == 63) wtot[w] = s;
    __syncthreads();
    int base = 0;
    #pragma unroll
    for (int w2 = 0; w2 < 4; ++w2) if (w2 < w) base += wtot[w2];
    const int n = wtot[0] + wtot[1] + wtot[2] + wtot[3];

    int pos = base + s - loc;
    if (mv.x == gmax) idx[pos++] = tid * 4 + 0;
    if (mv.y == gmax) idx[pos++] = tid * 4 + 1;
    if (mv.z == gmax) idx[pos++] = tid * 4 + 2;
    if (mv.w == gmax) idx[pos++] = tid * 4 + 3;
    __syncthreads();

    const float* xb_ = x + (size_t)(b << 10) * Cdim;
    float4 a0 = make_float4(0.f, 0.f, 0.f, 0.f);
    float4 a1 = make_float4(0.f, 0.f, 0.f, 0.f);
    int t = 0;
    for (; t + 1 < n; t += 2) {
        const float4 v0 = *(const float4*)(xb_ + (size_t)idx[t] * Cdim + tid * 4);
        const float4 v1 = *(const float4*)(xb_ + (size_t)idx[t + 1] * Cdim + tid * 4);
        a0.x += v0.x; a0.y += v0.y; a0.z += v0.z; a0.w += v0.w;
        a1.x += v1.x; a1.y += v1.y; a1.z += v1.z; a1.w += v1.w;
    }
    if (t < n) {
        const float4 v = *(const float4*)(xb_ + (size_t)idx[t] * Cdim + tid * 4);
        a0.x += v.x; a0.y += v.y; a0.z += v.z; a0.w += v.w;
    }
    const float inv = 1.0f / (float)n;
    ushort4 o;
    o.x = (ushort)bf16_rne((a0.x + a1.x) * inv);
    o.y = (ushort)bf16_rne((a0.y + a1.y) * inv);
    o.z = (ushort)bf16_rne((a0.z + a1.z) * inv);
    o.w = (ushort)bf16_rne((a0.w + a1.w) * inv);
    *(ushort4*)(Zb + (size_t)row * Cdim + tid * 4) = o;
}

// ---------------------------------------------------------------------------
// C[M][N] = A[M][K] @ W[N][K]^T (+ bias[N]), bf16 operands, f32 accum.
// 4 waves as 2x2 (wave tile BM/2 x BN/2); BK=64; 3-buffer pipeline with
// counted vmcnt + raw s_barrier (tiles t+1,t+2 in flight). XOR slot-swizzle
// on both the global source and the LDS read (rule 21).
// K3 geometry rationale (R13): K3 is LDS-read-THROUGHPUT-bound (48KB/block/
// K-step at 85 B/cyc = 18us, matches measurement). 128x128 block with 64x64
// wave-tiles cuts LDS bytes/MFMA 0.75 -> 0.5 KB (-33%). 1 block/CU is OK
// here because the bind is the LDS pipe (saturated by 4 waves), not the
// barrier drain that killed R5/R7 (those had BK=32 / bad read ratios).
// XSWZ: XCD k owns (Mrows/BM)/8 contiguous row-panels x all col-tiles ->
// A-slice (1MB) + whole W2 (2MB) resident in that XCD's 4MB L2.
template <int BM_, int BN_, bool OUT_BF16, bool HAS_BIAS, bool XSWZ>
__global__ __launch_bounds__(256) void gemm_bt(const ushort* __restrict__ A,
                                               const ushort* __restrict__ W,
                                               const float* __restrict__ bias,
                                               void* __restrict__ Cout,
                                               int Ncols) {
    constexpr int MI = BM_ / 32;        // 16-row frags per wave (M side)
    constexpr int NI = BN_ / 32;        // 16-col frags per wave (N side)
    constexpr int CA = BM_ / 32;        // A gload_lds issues per wave
    constexpr int CB = BN_ / 32;        // B gload_lds issues per wave
    constexpr int SI = CA + CB;
    __shared__ short As[3][BM_ * BK];
    __shared__ short Bs[3][BN_ * BK];
    const int tid  = threadIdx.x;
    const int lane = tid & 63;
    const int w    = tid >> 6;
    const int wr = w >> 1;
    const int wc = w & 1;
    const int fr = lane & 15;
    const int kg = lane >> 4;       // 0..3
    const int lr = lane >> 3;       // staging: row within 8-row group
    const int cs = lane & 7;        // staging: 16B slot within 128B row

    int bx, by;
    if constexpr (XSWZ) {
        constexpr int RPX = (Mrows / BM_) / 8;   // row-panels per XCD
        const int bid = blockIdx.x;     // 1-D grid
        const int k = bid & 7;          // XCD (round-robin dispatch)
        const int l = bid >> 3;
        by = k * RPX + (l % RPX);       // contiguous row-panels per XCD
        bx = l / RPX;                   // col-tile iterated within XCD
    } else {
        bx = blockIdx.x;
        by = blockIdx.y;
    }
    const int arow0 = by * BM_;
    const int ncol0 = bx * BN_;

    auto stage = [&](int b, int k0) {
        #pragma unroll
        for (int c = 0; c < CA; ++c) {
            const int r  = (w * CA + c) * 8 + lr;
            const int gs = cs ^ (r & 7);
            __builtin_amdgcn_global_load_lds(
                (gbl_b*)(A + (size_t)(arow0 + r) * KD + k0 + gs * 8),
                (lds_b*)&As[b][(w * CA + c) * 8 * BK], 16, 0, 0);
        }
        #pragma unroll
        for (int c = 0; c < CB; ++c) {
            const int r  = (w * CB + c) * 8 + lr;
            const int gs = cs ^ (r & 7);
            __builtin_amdgcn_global_load_lds(
                (gbl_b*)(W + (size_t)(ncol0 + r) * KD + k0 + gs * 8),
                (lds_b*)&Bs[b][(w * CB + c) * 8 * BK], 16, 0, 0);
        }
    };

    f32x4 acc[MI][NI] = {};

    stage(0, 0);
    stage(1, BK);

    int cur = 0;
    for (int t = 0; t < NT; ++t) {
        if (t < NT - 1) waitv<SI>();        // own tile-t landed; t+1 in flight
        else            waitv<0>();
        __builtin_amdgcn_s_barrier();       // all waves' tile-t staging visible
        __builtin_amdgcn_sched_barrier(0);

        if (t + 2 < NT) stage(cur + 2 >= 3 ? cur - 1 : cur + 2, (t + 2) * BK);

        s16x8 af[MI][2], bv_[NI][2];
        #pragma unroll
        for (int mi = 0; mi < MI; ++mi)
            #pragma unroll
            for (int ks = 0; ks < 2; ++ks) {
                const int row = wr * (BM_ / 2) + mi * 16 + fr;
                const int sl  = (ks * 4 + kg) ^ (row & 7);
                af[mi][ks] = *(const s16x8*)&As[cur][row * BK + sl * 8];
            }
        #pragma unroll
        for (int ni = 0; ni < NI; ++ni)
            #pragma unroll
            for (int ks = 0; ks < 2; ++ks) {
                const int row = wc * (BN_ / 2) + ni * 16 + fr;
                const int sl  = (ks * 4 + kg) ^ (row & 7);
                bv_[ni][ks] = *(const s16x8*)&Bs[cur][row * BK + sl * 8];
            }

        #pragma unroll
        for (int ks = 0; ks < 2; ++ks)
            #pragma unroll
            for (int mi = 0; mi < MI; ++mi)
                #pragma unroll
                for (int ni = 0; ni < NI; ++ni)
                    acc[mi][ni] = __builtin_amdgcn_mfma_f32_16x16x32_bf16(
                        af[mi][ks], bv_[ni][ks], acc[mi][ni], 0, 0, 0);

        cur = (cur + 1 == 3) ? 0 : cur + 1;
    }

    // Epilogue. C/D layout (m89-verified): col = lane&15, row = (lane>>4)*4 + j
    #pragma unroll
    for (int mi = 0; mi < MI; ++mi) {
        const int row0 = arow0 + wr * (BM_ / 2) + mi * 16 + kg * 4;
        #pragma unroll
        for (int ni = 0; ni < NI; ++ni) {
            const int col = ncol0 + wc * (BN_ / 2) + ni * 16 + fr;
            const float bs = HAS_BIAS ? bias[col] : 0.f;
            f32x4 r = acc[mi][ni];
            if (OUT_BF16) {
                ushort* o = (ushort*)Cout;
                #pragma unroll
                for (int j = 0; j < 4; ++j)
                    o[(size_t)(row0 + j) * Ncols + col] = (ushort)bf16_rne(r[j] + bs);
            } else {
                float* o = (float*)Cout;
                #pragma unroll
                for (int j = 0; j < 4; ++j)
                    o[(size_t)(row0 + j) * Ncols + col] = r[j] + bs;
            }
        }
    }
}

// ---------------------------------------------------------------------------
extern "C" void kernel_launch(void* const* d_in, const int* in_sizes, int n_in,
                              void* d_out, int out_size, void* d_ws, size_t ws_size,
                              hipStream_t stream) {
    const float* x      = (const float*)d_in[0];
    const int*   mask   = (const int*)d_in[1];
    const float* qkv_w  = (const float*)d_in[2];
    const float* qkv_b  = (const float*)d_in[3];
    const float* proj_w = (const float*)d_in[4];
    const float* proj_b = (const float*)d_in[5];
    // d_in[6] (rel_emb) is numerically dead in the f32 reference: the
    // (m-1)*1e9 mask offsets annihilate the dot terms under f32 rounding, so
    // softmax reduces to a uniform average over each row's argmax-m set.
    // Algebraic refactor:  out = (P@x) @ (pw@Wv)^T + (pw@bv + pb).
    float* out = (float*)d_out;

    // Workspace (bf16 ushorts unless noted): ~14 MB
    ushort* wvT   = (ushort*)d_ws;                   // [1024][1024]  Wv^T
    ushort* pwb   = wvT  + (size_t)Cdim * Cdim;      // [1024][1024]  bf16(pw)
    ushort* W2b   = pwb  + (size_t)Cdim * Cdim;      // [1024][1024]  pw@Wv
    ushort* Zb    = W2b  + (size_t)Cdim * Cdim;      // [4096][1024]  P@x
    float*  bias2 = (float*)(Zb + (size_t)Mrows * Cdim);  // [1024] f32

    const float* Wv = qkv_w + (size_t)2 * Cdim * Cdim;
    const float* bv = qkv_b + 2 * Cdim;

    // K1: weight prep (wvT, pwb, bias2) + mask-average Zb (f32 gather)
    prep_mask_kernel<<<dim3(512 + Mrows), 256, 0, stream>>>(
        x, mask, Wv, proj_w, bv, proj_b, wvT, pwb, bias2, Zb);
    // K2: W2 = bf16(pw @ Wv) == pwb @ wvT^T   (1024^3, 64x64 tiles, grid 256)
    gemm_bt<64, 64, true, false, false><<<dim3(Cdim / 64, Cdim / 64), 256, 0, stream>>>(
        pwb, wvT, nullptr, W2b, Cdim);
    // K3: out = Zb @ W2^T + bias2  (4096x1024x1024, 128x128 tiles, 256 blocks
    //     = 1/CU; 64x64 wave-tiles cut LDS bytes/output 33% — K3 is
    //     LDS-read-throughput-bound, so this is the binding resource)
    gemm_bt<128, 128, false, true, true><<<dim3(256), 256, 0, stream>>>(
        Zb, W2b, bias2, out, Cdim);
}

// Round 14
// 46.447 us; speedup vs baseline: 1.0814x; 1.0814x over previous
//
#include <hip/hip_runtime.h>
#include <hip/hip_bf16.h>
#include <stdint.h>

// Shapes (fixed by the problem)
constexpr int Bsz  = 4;
constexpr int Nseq = 1024;
constexpr int Cdim = 1024;
constexpr int Mrows = Bsz * Nseq;   // 4096
constexpr int KD = 1024;            // GEMM K (both GEMMs)
constexpr int BK = 64;              // K-step
constexpr int NT = KD / BK;         // 16 K-steps

typedef __attribute__((ext_vector_type(8))) short s16x8;
typedef __attribute__((ext_vector_type(4))) float f32x4;
typedef __attribute__((address_space(3))) unsigned char lds_b;
typedef __attribute__((address_space(1))) const unsigned char gbl_b;

__device__ inline short bf16_rne(float f) {
    union { float f; unsigned u; } c; c.f = f;
    unsigned u = c.u;
    u = u + 0x7FFFu + ((u >> 16) & 1u);
    return (short)(u >> 16);
}

template <int N> __device__ __forceinline__ void waitv() {
    if constexpr (N == 0)      asm volatile("s_waitcnt vmcnt(0)" ::: "memory");
    else if constexpr (N == 4) asm volatile("s_waitcnt vmcnt(4)" ::: "memory");
    else if constexpr (N == 6) asm volatile("s_waitcnt vmcnt(6)" ::: "memory");
    else static_assert(N == 0, "unsupported vmcnt");
}

// ---------------------------------------------------------------------------
// K1: fused prep + mask-average (grid 4608 x 256):
//   blocks [0,256):    wvT = bf16(Wv^T)          (64x64 LDS transpose tiles)
//   blocks [256,512):  bias2 = pw@bv+pb ; pwb = bf16(pw)
//   blocks [512,4608): Zb[row,:] = bf16(mean over argmax-mask cols j of x[b,j,:])
//                      XCD-grouped rows: each XCD gathers from ONE 4MB batch
//                      slice of f32 x -> L2-resident gather.
__global__ __launch_bounds__(256) void prep_mask_kernel(
        const float* __restrict__ x, const int* __restrict__ mask,
        const float* __restrict__ Wv, const float* __restrict__ pw,
        const float* __restrict__ bv, const float* __restrict__ pb,
        ushort* __restrict__ wvT, ushort* __restrict__ pwb,
        float* __restrict__ bias2, ushort* __restrict__ Zb) {
    const int bid = blockIdx.x;
    const int tid = threadIdx.x;
    if (bid < 256) {
        // ---- transpose-convert Wv -> wvT
        __shared__ ushort t[64][72];
        const int r0 = (bid >> 4) * 64, c0 = (bid & 15) * 64;
        const int lr = tid >> 4;
        const int lc = (tid & 15) * 4;
        #pragma unroll
        for (int p = 0; p < 4; ++p) {
            const int row = p * 16 + lr;
            const float4 v = *(const float4*)(Wv + (size_t)(r0 + row) * Cdim + c0 + lc);
            t[lc + 0][row] = (ushort)bf16_rne(v.x);
            t[lc + 1][row] = (ushort)bf16_rne(v.y);
            t[lc + 2][row] = (ushort)bf16_rne(v.z);
            t[lc + 3][row] = (ushort)bf16_rne(v.w);
        }
        __syncthreads();
        const int orow = tid >> 2;
        const int oc   = (tid & 3) * 16;
        const s16x8 a = *(const s16x8*)&t[orow][oc];
        const s16x8 b = *(const s16x8*)&t[orow][oc + 8];
        ushort* d = wvT + (size_t)(c0 + orow) * Cdim + r0 + oc;
        *(s16x8*)d = a;
        *(s16x8*)(d + 8) = b;
        return;
    }
    if (bid < 512) {
        // ---- bias2 + pw convert (one wave per row)
        const int j = (bid - 256) * 4 + (tid >> 6);
        const int l = tid & 63;
        float s = 0.f;
        #pragma unroll
        for (int c = 0; c < 4; ++c) {
            const float4 w = *(const float4*)(pw + (size_t)j * Cdim + c * 256 + l * 4);
            const float4 b = *(const float4*)(bv + c * 256 + l * 4);
            s += w.x * b.x + w.y * b.y + w.z * b.z + w.w * b.w;
            ushort4 o;
            o.x = (ushort)bf16_rne(w.x); o.y = (ushort)bf16_rne(w.y);
            o.z = (ushort)bf16_rne(w.z); o.w = (ushort)bf16_rne(w.w);
            *(ushort4*)(pwb + (size_t)j * Cdim + c * 256 + l * 4) = o;
        }
        #pragma unroll
        for (int off = 32; off > 0; off >>= 1) s += __shfl_xor(s, off);
        if (l == 0) bias2[j] = s + pb[j];
        return;
    }
    // ---- mask-average over f32 x (XCD-grouped rows)
    __shared__ int wmax[4];
    __shared__ int wtot[4];
    __shared__ int idx[1024];
    const int m   = bid - 512;
    const int row = (m & 7) * 512 + (m >> 3);   // XCD k -> rows [k*512,(k+1)*512)
    const int lane = tid & 63;
    const int w = tid >> 6;
    const int b = row >> 10;
    const int* mrow = mask + (size_t)row * Nseq;

    const int4 mv = ((const int4*)mrow)[tid];
    int lm = max(max(mv.x, mv.y), max(mv.z, mv.w));
    #pragma unroll
    for (int off = 32; off > 0; off >>= 1) lm = max(lm, __shfl_xor(lm, off));
    if (lane == 0) wmax[w] = lm;
    __syncthreads();
    const int gmax = max(max(wmax[0], wmax[1]), max(wmax[2], wmax[3]));

    const int loc = (mv.x == gmax) + (mv.y == gmax) + (mv.z == gmax) + (mv.w == gmax);
    int s = loc;   // inclusive shfl-scan within the wave
    #pragma unroll
    for (int off = 1; off < 64; off <<= 1) {
        const int o = __shfl_up(s, off, 64);
        if (lane >= off) s += o;
    }
    if (lane == 63) wtot[w] = s;
    __syncthreads();
    int base = 0;
    #pragma unroll
    for (int w2 = 0; w2 < 4; ++w2) if (w2 < w) base += wtot[w2];
    const int n = wtot[0] + wtot[1] + wtot[2] + wtot[3];

    int pos = base + s - loc;
    if (mv.x == gmax) idx[pos++] = tid * 4 + 0;
    if (mv.y == gmax) idx[pos++] = tid * 4 + 1;
    if (mv.z == gmax) idx[pos++] = tid * 4 + 2;
    if (mv.w == gmax) idx[pos++] = tid * 4 + 3;
    __syncthreads();

    const float* xb_ = x + (size_t)(b << 10) * Cdim;
    float4 a0 = make_float4(0.f, 0.f, 0.f, 0.f);
    float4 a1 = make_float4(0.f, 0.f, 0.f, 0.f);
    int t = 0;
    for (; t + 1 < n; t += 2) {
        const float4 v0 = *(const float4*)(xb_ + (size_t)idx[t] * Cdim + tid * 4);
        const float4 v1 = *(const float4*)(xb_ + (size_t)idx[t + 1] * Cdim + tid * 4);
        a0.x += v0.x; a0.y += v0.y; a0.z += v0.z; a0.w += v0.w;
        a1.x += v1.x; a1.y += v1.y; a1.z += v1.z; a1.w += v1.w;
    }
    if (t < n) {
        const float4 v = *(const float4*)(xb_ + (size_t)idx[t] * Cdim + tid * 4);
        a0.x += v.x; a0.y += v.y; a0.z += v.z; a0.w += v.w;
    }
    const float inv = 1.0f / (float)n;
    ushort4 o;
    o.x = (ushort)bf16_rne((a0.x + a1.x) * inv);
    o.y = (ushort)bf16_rne((a0.y + a1.y) * inv);
    o.z = (ushort)bf16_rne((a0.z + a1.z) * inv);
    o.w = (ushort)bf16_rne((a0.w + a1.w) * inv);
    *(ushort4*)(Zb + (size_t)row * Cdim + tid * 4) = o;
}

// ---------------------------------------------------------------------------
// C[M][N] = A[M][K] @ W[N][K]^T (+ bias[N]), bf16 operands, f32 accum.
// 4 waves as 2x2; BK=64; 3-buffer deep pipeline: tiles t+1,t+2 in flight
// across a raw s_barrier; each iter waits only vmcnt(CA+CB) (own oldest tile
// landed). XOR slot-swizzle on both the global source and the LDS read.
// [Final ledger: 2 blocks/CU sweet spot (1/CU loses — R5/R7/R13 3x; 3/CU
//  loses — R8); XSWZ row-chunk L2 mapping on K3 (R9 win); no heterogeneous
//  co-scheduling (R7/R10); no global A-frags (R11).]
template <int BM_, int BN_, bool OUT_BF16, bool HAS_BIAS, bool XSWZ>
__global__ __launch_bounds__(256) void gemm_bt(const ushort* __restrict__ A,
                                               const ushort* __restrict__ W,
                                               const float* __restrict__ bias,
                                               void* __restrict__ Cout,
                                               int Ncols) {
    constexpr int MI = BM_ / 32;        // 16-row frags per wave (M side)
    constexpr int NI = BN_ / 32;        // 16-col frags per wave (N side)
    constexpr int CA = BM_ / 32;        // A gload_lds issues per wave
    constexpr int CB = BN_ / 32;        // B gload_lds issues per wave
    constexpr int SI = CA + CB;
    __shared__ short As[3][BM_ * BK];
    __shared__ short Bs[3][BN_ * BK];
    const int tid  = threadIdx.x;
    const int lane = tid & 63;
    const int w    = tid >> 6;
    const int wr = w >> 1;
    const int wc = w & 1;
    const int fr = lane & 15;
    const int kg = lane >> 4;       // 0..3
    const int lr = lane >> 3;       // staging: row within 8-row group
    const int cs = lane & 7;        // staging: 16B slot within 128B row

    int bx, by;
    if constexpr (XSWZ) {
        const int bid = blockIdx.x;     // 512 blocks, 1-D
        const int k = bid & 7;          // XCD (round-robin dispatch)
        const int l = bid >> 3;         // 0..63 within XCD
        by = k * 8 + (l & 7);           // row-panel: 8 contiguous per XCD
        bx = l >> 3;                    // col-tile: iterated within XCD
    } else {
        bx = blockIdx.x;
        by = blockIdx.y;
    }
    const int arow0 = by * BM_;
    const int ncol0 = bx * BN_;

    auto stage = [&](int b, int k0) {
        #pragma unroll
        for (int c = 0; c < CA; ++c) {
            const int r  = (w * CA + c) * 8 + lr;
            const int gs = cs ^ (r & 7);
            __builtin_amdgcn_global_load_lds(
                (gbl_b*)(A + (size_t)(arow0 + r) * KD + k0 + gs * 8),
                (lds_b*)&As[b][(w * CA + c) * 8 * BK], 16, 0, 0);
        }
        #pragma unroll
        for (int c = 0; c < CB; ++c) {
            const int r  = (w * CB + c) * 8 + lr;
            const int gs = cs ^ (r & 7);
            __builtin_amdgcn_global_load_lds(
                (gbl_b*)(W + (size_t)(ncol0 + r) * KD + k0 + gs * 8),
                (lds_b*)&Bs[b][(w * CB + c) * 8 * BK], 16, 0, 0);
        }
    };

    f32x4 acc[MI][NI] = {};

    stage(0, 0);
    stage(1, BK);

    int cur = 0;
    for (int t = 0; t < NT; ++t) {
        if (t < NT - 1) waitv<SI>();        // own tile-t landed; t+1 in flight
        else            waitv<0>();
        __builtin_amdgcn_s_barrier();       // all waves' tile-t staging visible
        __builtin_amdgcn_sched_barrier(0);

        if (t + 2 < NT) stage(cur + 2 >= 3 ? cur - 1 : cur + 2, (t + 2) * BK);

        s16x8 af[MI][2], bv_[NI][2];
        #pragma unroll
        for (int mi = 0; mi < MI; ++mi)
            #pragma unroll
            for (int ks = 0; ks < 2; ++ks) {
                const int row = wr * (BM_ / 2) + mi * 16 + fr;
                const int sl  = (ks * 4 + kg) ^ (row & 7);
                af[mi][ks] = *(const s16x8*)&As[cur][row * BK + sl * 8];
            }
        #pragma unroll
        for (int ni = 0; ni < NI; ++ni)
            #pragma unroll
            for (int ks = 0; ks < 2; ++ks) {
                const int row = wc * (BN_ / 2) + ni * 16 + fr;
                const int sl  = (ks * 4 + kg) ^ (row & 7);
                bv_[ni][ks] = *(const s16x8*)&Bs[cur][row * BK + sl * 8];
            }

        #pragma unroll
        for (int ks = 0; ks < 2; ++ks)
            #pragma unroll
            for (int mi = 0; mi < MI; ++mi)
                #pragma unroll
                for (int ni = 0; ni < NI; ++ni)
                    acc[mi][ni] = __builtin_amdgcn_mfma_f32_16x16x32_bf16(
                        af[mi][ks], bv_[ni][ks], acc[mi][ni], 0, 0, 0);

        cur = (cur + 1 == 3) ? 0 : cur + 1;
    }

    // Epilogue. C/D layout (m89-verified): col = lane&15, row = (lane>>4)*4 + j
    #pragma unroll
    for (int mi = 0; mi < MI; ++mi) {
        const int row0 = arow0 + wr * (BM_ / 2) + mi * 16 + kg * 4;
        #pragma unroll
        for (int ni = 0; ni < NI; ++ni) {
            const int col = ncol0 + wc * (BN_ / 2) + ni * 16 + fr;
            const float bs = HAS_BIAS ? bias[col] : 0.f;
            f32x4 r = acc[mi][ni];
            if (OUT_BF16) {
                ushort* o = (ushort*)Cout;
                #pragma unroll
                for (int j = 0; j < 4; ++j)
                    o[(size_t)(row0 + j) * Ncols + col] = (ushort)bf16_rne(r[j] + bs);
            } else {
                float* o = (float*)Cout;
                #pragma unroll
                for (int j = 0; j < 4; ++j)
                    o[(size_t)(row0 + j) * Ncols + col] = r[j] + bs;
            }
        }
    }
}

// ---------------------------------------------------------------------------
extern "C" void kernel_launch(void* const* d_in, const int* in_sizes, int n_in,
                              void* d_out, int out_size, void* d_ws, size_t ws_size,
                              hipStream_t stream) {
    const float* x      = (const float*)d_in[0];
    const int*   mask   = (const int*)d_in[1];
    const float* qkv_w  = (const float*)d_in[2];
    const float* qkv_b  = (const float*)d_in[3];
    const float* proj_w = (const float*)d_in[4];
    const float* proj_b = (const float*)d_in[5];
    // d_in[6] (rel_emb) is numerically dead in the f32 reference: the
    // (m-1)*1e9 mask offsets annihilate the dot terms under f32 rounding, so
    // softmax reduces to a uniform average over each row's argmax-m set.
    // Algebraic refactor:  out = (P@x) @ (pw@Wv)^T + (pw@bv + pb).
    float* out = (float*)d_out;

    // Workspace (bf16 ushorts unless noted): ~14 MB
    ushort* wvT   = (ushort*)d_ws;                   // [1024][1024]  Wv^T
    ushort* pwb   = wvT  + (size_t)Cdim * Cdim;      // [1024][1024]  bf16(pw)
    ushort* W2b   = pwb  + (size_t)Cdim * Cdim;      // [1024][1024]  pw@Wv
    ushort* Zb    = W2b  + (size_t)Cdim * Cdim;      // [4096][1024]  P@x
    float*  bias2 = (float*)(Zb + (size_t)Mrows * Cdim);  // [1024] f32

    const float* Wv = qkv_w + (size_t)2 * Cdim * Cdim;
    const float* bv = qkv_b + 2 * Cdim;

    // K1: weight prep (wvT, pwb, bias2) + mask-average Zb (f32 gather)
    prep_mask_kernel<<<dim3(512 + Mrows), 256, 0, stream>>>(
        x, mask, Wv, proj_w, bv, proj_b, wvT, pwb, bias2, Zb);
    // K2: W2 = bf16(pw @ Wv) == pwb @ wvT^T   (1024^3, 64x64 tiles, grid 256)
    gemm_bt<64, 64, true, false, false><<<dim3(Cdim / 64, Cdim / 64), 256, 0, stream>>>(
        pwb, wvT, nullptr, W2b, Cdim);
    // K3: out = Zb @ W2^T + bias2  (4096x1024x1024, 64x128 tiles, 512 blocks
    //     = 2 blocks/CU; XCD row-chunk swizzle -> Zb slice + W2 L2-resident)
    gemm_bt<64, 128, false, true, true><<<dim3(512), 256, 0, stream>>>(
        Zb, W2b, bias2, out, Cdim);
}